// Round 5
// baseline (120.281 us; speedup 1.0000x reference)
//
#include <hip/hip_runtime.h>
#include <math.h>

#define DIM 64
#define HEADS 4
#define BB 8
#define QQ 128
#define VV 128
#define NN (BB*QQ)   // 1024

typedef float f2 __attribute__((ext_vector_type(2)));
typedef float f4 __attribute__((ext_vector_type(4)));

// ---- DPP helpers (VALU, no DS); CTRL is a compile-time template constant ----
template <int CTRL>
__device__ __forceinline__ float dppf(float x) {
    return __int_as_float(__builtin_amdgcn_update_dpp(
        0, __float_as_int(x), CTRL, 0xF, 0xF, true));
}
#define SWAP1 0xB1   // quad_perm(1,0,3,2): xor-1 partner
#define WSHR1 0x138  // wave_shr:1 : lane j <- j-1
#define WSHL1 0x130  // wave_shl:1 : lane j <- j+1

__device__ __forceinline__ f2 b2(float s) { f2 r; r.x = s; r.y = s; return r; }
#define SW(v) __builtin_shufflevector((v), (v), 1, 0)
#define FMA2(a, b, c) __builtin_elementwise_fma((a), (b), (c))

// async global->LDS DMA, 16 B per lane; LDS dest = wave-uniform base + lane*16
__device__ __forceinline__ void gl_lds16(const f4* g, f4* l) {
    __builtin_amdgcn_global_load_lds(
        (const __attribute__((address_space(1))) void*)g,
        (__attribute__((address_space(3))) void*)l, 16, 0, 0);
}

// K1: AvP[h][rp][j] = float4 {re,im of v-row 2rp ; re,im of v-row 2rp+1}
//     (re,im)[row][j] = sum_i values[row,i] * U[h, 64+i, j]
// Block 0 additionally precomputes the per-(h,j) recurrence coefficients
// (all trig) into Coef[10][256].
__global__ __launch_bounds__(256) void k_av(const float* __restrict__ values,
                                            const float* __restrict__ U_re,
                                            const float* __restrict__ U_im,
                                            const float* __restrict__ bias,
                                            const float* __restrict__ theta1,
                                            const float* __restrict__ phi1,
                                            const float* __restrict__ theta2,
                                            const float* __restrict__ phi2,
                                            const float* __restrict__ omega,
                                            f4* __restrict__ AvP,
                                            float* __restrict__ Coef) {
    int tid = blockIdx.x * blockDim.x + threadIdx.x;
    int w = tid >> 6;            // 0..2047
    int j = tid & 63;
    int h = w >> 9;              // 0..3
    int rp = w & 511;            // v-row pair within head
    int r0 = rp << 1;
    const float* vrow = values + r0 * DIM;                     // wave-uniform
    const float* ur = U_re + (h * 2 * DIM + DIM) * DIM + j;    // bottom half
    const float* ui = U_im + (h * 2 * DIM + DIM) * DIM + j;
    f2 a0 = 0.f, a1 = 0.f;
    #pragma unroll 8
    for (int i = 0; i < DIM; ++i) {
        f2 u; u.x = ur[i * DIM]; u.y = ui[i * DIM];
        a0 += vrow[i] * u;
        a1 += vrow[DIM + i] * u;
    }
    f4 o; o.x = a0.x; o.y = a0.y; o.z = a1.x; o.w = a1.y;
    AvP[(h * 512 + rp) * 64 + j] = o;      // one dwordx4 store

    if (blockIdx.x == 0) {
        int t = threadIdx.x;
        int hh = t >> 6, jj = t & 63;
        int k1 = jj >> 1;
        float th1 = theta1[hh * 32 + k1], ph1 = phi1[hh * 32 + k1];
        float C1 = cosf(th1), s1v = sinf(th1);
        float S1, E1r, E1i;
        if ((jj & 1) == 0) { S1 = -s1v; E1r = cosf(ph1); E1i = sinf(ph1); }
        else               { S1 =  s1v; E1r = 1.f;       E1i = 0.f;       }
        float C2, SL, SR, p2r, p2i;
        if (jj == 0 || jj == 63) {
            C2 = 1.f; SL = 0.f; SR = 0.f; p2r = 1.f; p2i = 0.f;
        } else {
            int k2 = (jj - 1) >> 1;
            float th2 = theta2[hh * 31 + k2], ph2 = phi2[hh * 31 + k2];
            float c2 = cosf(th2), s2 = sinf(th2);
            if (jj & 1) { C2 = c2; SL = -s2; SR = 0.f; p2r = cosf(ph2); p2i = sinf(ph2); }
            else        { C2 = c2; SR =  s2; SL = 0.f; p2r = 1.f;       p2i = 0.f;      }
        }
        float om = omega[hh * 64 + jj];
        float eor = cosf(om), eoi = sinf(om);
        float PHr = p2r * eor - p2i * eoi;
        float PHi = p2r * eoi + p2i * eor;
        Coef[0 * 256 + t] = C1;
        Coef[1 * 256 + t] = S1;
        Coef[2 * 256 + t] = E1r;
        Coef[3 * 256 + t] = E1i;
        Coef[4 * 256 + t] = C2;
        Coef[5 * 256 + t] = SL;
        Coef[6 * 256 + t] = SR;
        Coef[7 * 256 + t] = PHr;
        Coef[8 * 256 + t] = PHi;
        Coef[9 * 256 + t] = bias[hh * 64 + jj];
    }
}

// K2: 1024 blocks (one query row) x 4 waves (one head each). Av is staged
// into LDS by async global_load_lds DMA, double-buffered in 8 chunks of 16
// timesteps (64 KB LDS -> 2 blocks/CU). The DMA cannot be collapsed by the
// register allocator (unlike the register dbuf, which the compiler sank to
// per-step global loads = per-step L2/L3 latency on the serial chain); the
// end-of-chunk __syncthreads drains vmcnt, so stage(c+1) completes under
// chunk c's ~770 cy of compute. Per-step critical path is now VALU + hoisted
// ds_read only. Packed f2 step identical to the verified kernel.
__global__ __launch_bounds__(256, 2) void k_rnn_dense(
        const float* __restrict__ queries,
        const float* __restrict__ U_re,
        const float* __restrict__ U_im,
        const float* __restrict__ Coef,
        const f4* __restrict__ AvP,
        const float* __restrict__ W_dense,
        const float* __restrict__ b_dense,
        float* __restrict__ y) {
    __shared__ f4 sAv[2][HEADS][8][64];    // 64 KB, double-buffered chunk
    int n = blockIdx.x;        // 0..1023 (query row)
    int t = threadIdx.x;
    int h = t >> 6;            // head = wave
    int j = t & 63;            // state dim = lane
    int b = n >> 7;

    // wave h stages its head's 8 f4-pairs (16 timesteps) of chunk c
    const f4* gsrc = AvP + (h * 512 + b * 64) * 64 + j;
    auto stage = [&](int pb, int c) {
        const f4* g = gsrc + c * 8 * 64;
        #pragma unroll
        for (int pp = 0; pp < 8; ++pp)
            gl_lds16(g + pp * 64, &sAv[pb][h][pp][0]);
    };

    stage(0, 0);   // issue chunk 0; latency covered by the preamble below

    // ---- coefficients: 10 coalesced loads ----
    float C1  = Coef[0 * 256 + t];
    float S1  = Coef[1 * 256 + t];
    float E1r = Coef[2 * 256 + t];
    float E1i = Coef[3 * 256 + t];
    float C2  = Coef[4 * 256 + t];
    float SL  = Coef[5 * 256 + t];
    float SR  = Coef[6 * 256 + t];
    float PHr = Coef[7 * 256 + t];
    float PHi = Coef[8 * 256 + t];
    float bj  = Coef[9 * 256 + t];

    f2 C1p = b2(C1), S1p = b2(S1), E1rp = b2(E1r);
    f2 E1in; E1in.x = -E1i; E1in.y = E1i;
    f2 C2p = b2(C2), SLp = b2(SL), SRp = b2(SR), PHrp = b2(PHr);
    f2 PHin; PHin.x = -PHi; PHin.y = PHi;

    // ---- Aq: uq = q_row . U_top[h] ----
    const float* q0 = queries + n * DIM;         // block-uniform
    const float* ur = U_re + (h * 2 * DIM) * DIM + j;
    const float* ui = U_im + (h * 2 * DIM) * DIM + j;
    f2 uq = 0.f;
    #pragma unroll 8
    for (int i = 0; i < DIM; ++i) {
        f2 u; u.x = ur[i * DIM]; u.y = ui[i * DIM];
        uq = FMA2(b2(q0[i]), u, uq);
    }

    f2 hS = 0.f;
    // packed step: identical op sequence to the verified kernel
    auto step = [&](f2 av) {
        f2 uv = uq + av;
        f2 p; p.x = dppf<SWAP1>(hS.x); p.y = dppf<SWAP1>(hS.y);
        f2 tp = FMA2(C1p, hS, S1p * p);
        f2 T  = FMA2(E1rp, tp, E1in * SW(tp));
        f2 L; L.x = dppf<WSHL1>(T.x); L.y = dppf<WSHL1>(T.y);
        f2 R; R.x = dppf<WSHR1>(T.x); R.y = dppf<WSHR1>(T.y);
        f2 sp = FMA2(C2p, T, FMA2(SLp, L, SRp * R));
        f2 z  = FMA2(PHrp, sp, FMA2(PHin, SW(sp), uv));
        float q2 = fmaf(z.x, z.x, fmaf(z.y, z.y, 1e-10f));
        float rs = __builtin_amdgcn_rsqf(q2);
        float sc = fmaxf(fmaf(bj, rs, 1.f), 0.f);
        hS = z * b2(sc);
    };

    __syncthreads();   // chunk 0 staged (vmcnt drained by barrier semantics)

    // ---- scan: 8 chunks x 16 steps, 2-phase LDS double buffer ----
    for (int c = 0; c < 8; ++c) {
        int cb = c & 1;
        if (c < 7) stage(cb ^ 1, c + 1);     // issue BEFORE compute (T3)
        f4 ch[8];
        #pragma unroll
        for (int pp = 0; pp < 8; ++pp) ch[pp] = sAv[cb][h][pp][j];
        #pragma unroll
        for (int pp = 0; pp < 8; ++pp) {
            f2 a; a.x = ch[pp].x; a.y = ch[pp].y;
            step(a);                          // timestep 16c + 2pp
            f2 d; d.x = ch[pp].z; d.y = ch[pp].w;
            step(d);                          // timestep 16c + 2pp + 1
        }
        __syncthreads();                      // stage(c+1) done; buf reusable
    }

    // ---- fused dense for row n (reuse sAv LDS; all reads of it are done) --
    float* s_acc = (float*)&sAv[0][0][0][0];        // 256 floats
    float* s_part = s_acc + 256;                    // 256 floats
    s_acc[h * 64 + j] = hS.x;              // Re(hT)
    __syncthreads();

    {   // thread t: k-quarter qq = t>>6, col jj = t&63
        int qq = t >> 6, jj = t & 63;
        const float* Wp = W_dense + (qq * 64) * DIM + jj;
        const float* ap = &s_acc[qq * 64];
        float part = 0.f;
        #pragma unroll 8
        for (int k = 0; k < 64; ++k)
            part = fmaf(ap[k], Wp[k * DIM], part);   // ap broadcast, Wp coalesced
        s_part[t] = part;
    }
    __syncthreads();
    if (t < 64) {
        y[n * DIM + t] = b_dense[t] + s_part[t] + s_part[64 + t]
                       + s_part[128 + t] + s_part[192 + t];
    }
}

extern "C" void kernel_launch(void* const* d_in, const int* in_sizes, int n_in,
                              void* d_out, int out_size, void* d_ws, size_t ws_size,
                              hipStream_t stream) {
    const float* queries = (const float*)d_in[0];
    const float* values  = (const float*)d_in[1];
    const float* U_re    = (const float*)d_in[2];
    const float* U_im    = (const float*)d_in[3];
    const float* bias    = (const float*)d_in[4];
    const float* theta1  = (const float*)d_in[5];
    const float* phi1    = (const float*)d_in[6];
    const float* theta2  = (const float*)d_in[7];
    const float* phi2    = (const float*)d_in[8];
    const float* omega   = (const float*)d_in[9];
    const float* W_dense = (const float*)d_in[10];
    const float* b_dense = (const float*)d_in[11];
    float* y = (float*)d_out;

    f4* AvP = (f4*)d_ws;                              // 2 MB
    float* Coef = (float*)((char*)d_ws + HEADS * 512 * 64 * sizeof(f4));  // 10 KB

    k_av<<<512, 256, 0, stream>>>(values, U_re, U_im, bias, theta1, phi1,
                                  theta2, phi2, omega, AvP, Coef);
    k_rnn_dense<<<1024, 256, 0, stream>>>(queries, U_re, U_im, Coef, AvP,
                                          W_dense, b_dense, y);
}

// Round 6
// 114.684 us; speedup vs baseline: 1.0488x; 1.0488x over previous
//
#include <hip/hip_runtime.h>
#include <math.h>

#define DIM 64
#define HEADS 4
#define BB 8
#define QQ 128
#define VV 128
#define NN (BB*QQ)   // 1024

typedef float f2 __attribute__((ext_vector_type(2)));
typedef float f4 __attribute__((ext_vector_type(4)));

// ---- DPP helpers (VALU, no DS); CTRL is a compile-time template constant ----
template <int CTRL>
__device__ __forceinline__ float dppf(float x) {
    return __int_as_float(__builtin_amdgcn_update_dpp(
        0, __float_as_int(x), CTRL, 0xF, 0xF, true));
}
#define SWAP1 0xB1   // quad_perm(1,0,3,2): xor-1 partner
#define WSHR1 0x138  // wave_shr:1 : lane j <- j-1
#define WSHL1 0x130  // wave_shl:1 : lane j <- j+1

__device__ __forceinline__ f2 b2(float s) { f2 r; r.x = s; r.y = s; return r; }
#define SW(v) __builtin_shufflevector((v), (v), 1, 0)
#define FMA2(a, b, c) __builtin_elementwise_fma((a), (b), (c))

// async global->LDS DMA, 16 B per lane; LDS dest = wave-uniform base + lane*16
__device__ __forceinline__ void gl_lds16(const f4* g, f4* l) {
    __builtin_amdgcn_global_load_lds(
        (const __attribute__((address_space(1))) void*)g,
        (__attribute__((address_space(3))) void*)l, 16, 0, 0);
}

// K1: AvP[h][rp][j] = float4 {re,im of v-row 2rp ; re,im of v-row 2rp+1}
//     (re,im)[row][j] = sum_i values[row,i] * U[h, 64+i, j]
// Block 0 additionally precomputes the per-(h,j) recurrence coefficients
// (all trig) into Coef[10][256].
__global__ __launch_bounds__(256) void k_av(const float* __restrict__ values,
                                            const float* __restrict__ U_re,
                                            const float* __restrict__ U_im,
                                            const float* __restrict__ bias,
                                            const float* __restrict__ theta1,
                                            const float* __restrict__ phi1,
                                            const float* __restrict__ theta2,
                                            const float* __restrict__ phi2,
                                            const float* __restrict__ omega,
                                            f4* __restrict__ AvP,
                                            float* __restrict__ Coef) {
    int tid = blockIdx.x * blockDim.x + threadIdx.x;
    int w = tid >> 6;            // 0..2047
    int j = tid & 63;
    int h = w >> 9;              // 0..3
    int rp = w & 511;            // v-row pair within head
    int r0 = rp << 1;
    const float* vrow = values + r0 * DIM;                     // wave-uniform
    const float* ur = U_re + (h * 2 * DIM + DIM) * DIM + j;    // bottom half
    const float* ui = U_im + (h * 2 * DIM + DIM) * DIM + j;
    f2 a0 = 0.f, a1 = 0.f;
    #pragma unroll 8
    for (int i = 0; i < DIM; ++i) {
        f2 u; u.x = ur[i * DIM]; u.y = ui[i * DIM];
        a0 += vrow[i] * u;
        a1 += vrow[DIM + i] * u;
    }
    f4 o; o.x = a0.x; o.y = a0.y; o.z = a1.x; o.w = a1.y;
    AvP[(h * 512 + rp) * 64 + j] = o;      // one dwordx4 store

    if (blockIdx.x == 0) {
        int t = threadIdx.x;
        int hh = t >> 6, jj = t & 63;
        int k1 = jj >> 1;
        float th1 = theta1[hh * 32 + k1], ph1 = phi1[hh * 32 + k1];
        float C1 = cosf(th1), s1v = sinf(th1);
        float S1, E1r, E1i;
        if ((jj & 1) == 0) { S1 = -s1v; E1r = cosf(ph1); E1i = sinf(ph1); }
        else               { S1 =  s1v; E1r = 1.f;       E1i = 0.f;       }
        float C2, SL, SR, p2r, p2i;
        if (jj == 0 || jj == 63) {
            C2 = 1.f; SL = 0.f; SR = 0.f; p2r = 1.f; p2i = 0.f;
        } else {
            int k2 = (jj - 1) >> 1;
            float th2 = theta2[hh * 31 + k2], ph2 = phi2[hh * 31 + k2];
            float c2 = cosf(th2), s2 = sinf(th2);
            if (jj & 1) { C2 = c2; SL = -s2; SR = 0.f; p2r = cosf(ph2); p2i = sinf(ph2); }
            else        { C2 = c2; SR =  s2; SL = 0.f; p2r = 1.f;       p2i = 0.f;      }
        }
        float om = omega[hh * 64 + jj];
        float eor = cosf(om), eoi = sinf(om);
        float PHr = p2r * eor - p2i * eoi;
        float PHi = p2r * eoi + p2i * eor;
        Coef[0 * 256 + t] = C1;
        Coef[1 * 256 + t] = S1;
        Coef[2 * 256 + t] = E1r;
        Coef[3 * 256 + t] = E1i;
        Coef[4 * 256 + t] = C2;
        Coef[5 * 256 + t] = SL;
        Coef[6 * 256 + t] = SR;
        Coef[7 * 256 + t] = PHr;
        Coef[8 * 256 + t] = PHi;
        Coef[9 * 256 + t] = bias[hh * 64 + jj];
    }
}

// K2: 1024 blocks (one query row) x 4 waves (one head each). Av staged into
// LDS by async DMA, double-buffered in 16 chunks of 8 timesteps: 32 KB LDS
// -> 4 blocks/CU = 4 waves/SIMD (vs 2 at 64 KB). The serial ~85-cy/step
// dependency chain of one wave is covered by the other three; issue demand
// (4 x ~90 cy) oversubscribes the SIMD -> VALU duty ~85%+. Per-step reads
// are ds_read (off-chain); the end-of-chunk barrier drains the stage DMA
// under 8 steps of compute. Packed f2 step identical to the verified kernel.
__global__ __launch_bounds__(256, 4) void k_rnn_dense(
        const float* __restrict__ queries,
        const float* __restrict__ U_re,
        const float* __restrict__ U_im,
        const float* __restrict__ Coef,
        const f4* __restrict__ AvP,
        const float* __restrict__ W_dense,
        const float* __restrict__ b_dense,
        float* __restrict__ y) {
    __shared__ f4 sAv[2][HEADS][4][64];    // 32 KB, double-buffered chunk
    int n = blockIdx.x;        // 0..1023 (query row)
    int t = threadIdx.x;
    int h = t >> 6;            // head = wave
    int j = t & 63;            // state dim = lane
    int b = n >> 7;

    // wave h stages its head's 4 f4-pairs (8 timesteps) of chunk c
    const f4* gsrc = AvP + (h * 512 + b * 64) * 64 + j;
    auto stage = [&](int pb, int c) {
        const f4* g = gsrc + c * 4 * 64;
        #pragma unroll
        for (int pp = 0; pp < 4; ++pp)
            gl_lds16(g + pp * 64, &sAv[pb][h][pp][0]);
    };

    stage(0, 0);   // issue chunk 0; latency covered by the preamble below

    // ---- coefficients: 10 coalesced loads ----
    float C1  = Coef[0 * 256 + t];
    float S1  = Coef[1 * 256 + t];
    float E1r = Coef[2 * 256 + t];
    float E1i = Coef[3 * 256 + t];
    float C2  = Coef[4 * 256 + t];
    float SL  = Coef[5 * 256 + t];
    float SR  = Coef[6 * 256 + t];
    float PHr = Coef[7 * 256 + t];
    float PHi = Coef[8 * 256 + t];
    float bj  = Coef[9 * 256 + t];

    f2 C1p = b2(C1), S1p = b2(S1), E1rp = b2(E1r);
    f2 E1in; E1in.x = -E1i; E1in.y = E1i;
    f2 C2p = b2(C2), SLp = b2(SL), SRp = b2(SR), PHrp = b2(PHr);
    f2 PHin; PHin.x = -PHi; PHin.y = PHi;

    // ---- Aq: uq = q_row . U_top[h] ----
    const float* q0 = queries + n * DIM;         // block-uniform
    const float* ur = U_re + (h * 2 * DIM) * DIM + j;
    const float* ui = U_im + (h * 2 * DIM) * DIM + j;
    f2 uq = 0.f;
    #pragma unroll 8
    for (int i = 0; i < DIM; ++i) {
        f2 u; u.x = ur[i * DIM]; u.y = ui[i * DIM];
        uq = FMA2(b2(q0[i]), u, uq);
    }

    f2 hS = 0.f;
    // packed step: identical op sequence to the verified kernel
    auto step = [&](f2 av) {
        f2 uv = uq + av;
        f2 p; p.x = dppf<SWAP1>(hS.x); p.y = dppf<SWAP1>(hS.y);
        f2 tp = FMA2(C1p, hS, S1p * p);
        f2 T  = FMA2(E1rp, tp, E1in * SW(tp));
        f2 L; L.x = dppf<WSHL1>(T.x); L.y = dppf<WSHL1>(T.y);
        f2 R; R.x = dppf<WSHR1>(T.x); R.y = dppf<WSHR1>(T.y);
        f2 sp = FMA2(C2p, T, FMA2(SLp, L, SRp * R));
        f2 z  = FMA2(PHrp, sp, FMA2(PHin, SW(sp), uv));
        float q2 = fmaf(z.x, z.x, fmaf(z.y, z.y, 1e-10f));
        float rs = __builtin_amdgcn_rsqf(q2);
        float sc = fmaxf(fmaf(bj, rs, 1.f), 0.f);
        hS = z * b2(sc);
    };

    __syncthreads();   // chunk 0 staged (vmcnt drained by barrier semantics)

    // ---- scan: 16 chunks x 8 steps, 2-phase LDS double buffer ----
    for (int c = 0; c < 16; ++c) {
        int cb = c & 1;
        if (c < 15) stage(cb ^ 1, c + 1);    // issue BEFORE compute (T3)
        f4 ch[4];
        #pragma unroll
        for (int pp = 0; pp < 4; ++pp) ch[pp] = sAv[cb][h][pp][j];
        #pragma unroll
        for (int pp = 0; pp < 4; ++pp) {
            f2 a; a.x = ch[pp].x; a.y = ch[pp].y;
            step(a);                          // timestep 8c + 2pp
            f2 d; d.x = ch[pp].z; d.y = ch[pp].w;
            step(d);                          // timestep 8c + 2pp + 1
        }
        __syncthreads();                      // stage(c+1) done; buf reusable
    }

    // ---- fused dense for row n (reuse sAv LDS; all reads of it are done) --
    float* s_acc = (float*)&sAv[0][0][0][0];        // 256 floats
    float* s_part = s_acc + 256;                    // 256 floats
    s_acc[h * 64 + j] = hS.x;              // Re(hT)
    __syncthreads();

    {   // thread t: k-quarter qq = t>>6, col jj = t&63
        int qq = t >> 6, jj = t & 63;
        const float* Wp = W_dense + (qq * 64) * DIM + jj;
        const float* ap = &s_acc[qq * 64];
        float part = 0.f;
        #pragma unroll 8
        for (int k = 0; k < 64; ++k)
            part = fmaf(ap[k], Wp[k * DIM], part);   // ap broadcast, Wp coalesced
        s_part[t] = part;
    }
    __syncthreads();
    if (t < 64) {
        y[n * DIM + t] = b_dense[t] + s_part[t] + s_part[64 + t]
                       + s_part[128 + t] + s_part[192 + t];
    }
}

extern "C" void kernel_launch(void* const* d_in, const int* in_sizes, int n_in,
                              void* d_out, int out_size, void* d_ws, size_t ws_size,
                              hipStream_t stream) {
    const float* queries = (const float*)d_in[0];
    const float* values  = (const float*)d_in[1];
    const float* U_re    = (const float*)d_in[2];
    const float* U_im    = (const float*)d_in[3];
    const float* bias    = (const float*)d_in[4];
    const float* theta1  = (const float*)d_in[5];
    const float* phi1    = (const float*)d_in[6];
    const float* theta2  = (const float*)d_in[7];
    const float* phi2    = (const float*)d_in[8];
    const float* omega   = (const float*)d_in[9];
    const float* W_dense = (const float*)d_in[10];
    const float* b_dense = (const float*)d_in[11];
    float* y = (float*)d_out;

    f4* AvP = (f4*)d_ws;                              // 2 MB
    float* Coef = (float*)((char*)d_ws + HEADS * 512 * 64 * sizeof(f4));  // 10 KB

    k_av<<<512, 256, 0, stream>>>(values, U_re, U_im, bias, theta1, phi1,
                                  theta2, phi2, omega, AvP, Coef);
    k_rnn_dense<<<1024, 256, 0, stream>>>(queries, U_re, U_im, Coef, AvP,
                                          W_dense, b_dense, y);
}

// Round 7
// 111.702 us; speedup vs baseline: 1.0768x; 1.0267x over previous
//
#include <hip/hip_runtime.h>
#include <math.h>

#define DIM 64
#define HEADS 4
#define BB 8
#define QQ 128
#define VV 128
#define NN (BB*QQ)   // 1024

typedef float f2 __attribute__((ext_vector_type(2)));
typedef float f4 __attribute__((ext_vector_type(4)));

// ---- DPP helpers (VALU, no DS); CTRL is a compile-time template constant ----
template <int CTRL>
__device__ __forceinline__ float dppf(float x) {
    return __int_as_float(__builtin_amdgcn_update_dpp(
        0, __float_as_int(x), CTRL, 0xF, 0xF, true));
}
#define SWAP1 0xB1   // quad_perm(1,0,3,2): xor-1 partner
#define WSHR1 0x138  // wave_shr:1 : lane j <- j-1
#define WSHL1 0x130  // wave_shl:1 : lane j <- j+1

__device__ __forceinline__ f2 b2(float s) { f2 r; r.x = s; r.y = s; return r; }
#define SW(v) __builtin_shufflevector((v), (v), 1, 0)
#define FMA2(a, b, c) __builtin_elementwise_fma((a), (b), (c))

// K1: AvP[h][rp][j] = float4 {re,im of v-row 2rp ; re,im of v-row 2rp+1}
//     (re,im)[row][j] = sum_i values[row,i] * U[h, 64+i, j]
// Block 0 additionally precomputes the per-(h,j) recurrence coefficients
// (all trig) into Coef[10][256].
__global__ __launch_bounds__(256) void k_av(const float* __restrict__ values,
                                            const float* __restrict__ U_re,
                                            const float* __restrict__ U_im,
                                            const float* __restrict__ bias,
                                            const float* __restrict__ theta1,
                                            const float* __restrict__ phi1,
                                            const float* __restrict__ theta2,
                                            const float* __restrict__ phi2,
                                            const float* __restrict__ omega,
                                            f4* __restrict__ AvP,
                                            float* __restrict__ Coef) {
    int tid = blockIdx.x * blockDim.x + threadIdx.x;
    int w = tid >> 6;            // 0..2047
    int j = tid & 63;
    int h = w >> 9;              // 0..3
    int rp = w & 511;            // v-row pair within head
    int r0 = rp << 1;
    const float* vrow = values + r0 * DIM;                     // wave-uniform
    const float* ur = U_re + (h * 2 * DIM + DIM) * DIM + j;    // bottom half
    const float* ui = U_im + (h * 2 * DIM + DIM) * DIM + j;
    f2 a0 = 0.f, a1 = 0.f;
    #pragma unroll 8
    for (int i = 0; i < DIM; ++i) {
        f2 u; u.x = ur[i * DIM]; u.y = ui[i * DIM];
        a0 += vrow[i] * u;
        a1 += vrow[DIM + i] * u;
    }
    f4 o; o.x = a0.x; o.y = a0.y; o.z = a1.x; o.w = a1.y;
    AvP[(h * 512 + rp) * 64 + j] = o;      // one dwordx4 store

    if (blockIdx.x == 0) {
        int t = threadIdx.x;
        int hh = t >> 6, jj = t & 63;
        int k1 = jj >> 1;
        float th1 = theta1[hh * 32 + k1], ph1 = phi1[hh * 32 + k1];
        float C1 = cosf(th1), s1v = sinf(th1);
        float S1, E1r, E1i;
        if ((jj & 1) == 0) { S1 = -s1v; E1r = cosf(ph1); E1i = sinf(ph1); }
        else               { S1 =  s1v; E1r = 1.f;       E1i = 0.f;       }
        float C2, SL, SR, p2r, p2i;
        if (jj == 0 || jj == 63) {
            C2 = 1.f; SL = 0.f; SR = 0.f; p2r = 1.f; p2i = 0.f;
        } else {
            int k2 = (jj - 1) >> 1;
            float th2 = theta2[hh * 31 + k2], ph2 = phi2[hh * 31 + k2];
            float c2 = cosf(th2), s2 = sinf(th2);
            if (jj & 1) { C2 = c2; SL = -s2; SR = 0.f; p2r = cosf(ph2); p2i = sinf(ph2); }
            else        { C2 = c2; SR =  s2; SL = 0.f; p2r = 1.f;       p2i = 0.f;      }
        }
        float om = omega[hh * 64 + jj];
        float eor = cosf(om), eoi = sinf(om);
        float PHr = p2r * eor - p2i * eoi;
        float PHi = p2r * eoi + p2i * eor;
        Coef[0 * 256 + t] = C1;
        Coef[1 * 256 + t] = S1;
        Coef[2 * 256 + t] = E1r;
        Coef[3 * 256 + t] = E1i;
        Coef[4 * 256 + t] = C2;
        Coef[5 * 256 + t] = SL;
        Coef[6 * 256 + t] = SR;
        Coef[7 * 256 + t] = PHr;
        Coef[8 * 256 + t] = PHi;
        Coef[9 * 256 + t] = bias[hh * 64 + jj];
    }
}

// K2: 256 blocks (block = query-row QUAD, same batch) x 4 waves (head per
// wave). Each wave runs FOUR independent recurrence chains sharing every Av
// load (1 f4 = 2 timesteps feeds all 4 chains). Evidence (R0/R3/R6): duty
// tracks chains-per-wave, not waves-per-SIMD -- the ~90-cy/step dependency
// chain self-stalls a 1-chain wave ~50% and co-resident waves don't cover
// it. 4 chains give ~10 independent ops at every point of the chain ->
// issue-bound. Barrier-free scan, register-window loads (best-measured R3
// structure). launch_bounds(256,1): 1 block/CU, VGPR headroom for 4 chains.
__global__ __launch_bounds__(256, 1) void k_rnn_dense(
        const float* __restrict__ queries,
        const float* __restrict__ U_re,
        const float* __restrict__ U_im,
        const float* __restrict__ Coef,
        const f4* __restrict__ AvP,
        const float* __restrict__ W_dense,
        const float* __restrict__ b_dense,
        float* __restrict__ y) {
    int m = blockIdx.x;        // 0..255 (row quad)
    int n0 = m << 2;           // rows n0..n0+3 (same batch b)
    int t = threadIdx.x;
    int h = t >> 6;            // head = wave
    int j = t & 63;            // state dim = lane
    int b = n0 >> 7;

    // ---- coefficients: 10 coalesced loads ----
    float C1  = Coef[0 * 256 + t];
    float S1  = Coef[1 * 256 + t];
    float E1r = Coef[2 * 256 + t];
    float E1i = Coef[3 * 256 + t];
    float C2  = Coef[4 * 256 + t];
    float SL  = Coef[5 * 256 + t];
    float SR  = Coef[6 * 256 + t];
    float PHr = Coef[7 * 256 + t];
    float PHi = Coef[8 * 256 + t];
    float bj  = Coef[9 * 256 + t];

    f2 C1p = b2(C1), S1p = b2(S1), E1rp = b2(E1r);
    f2 E1in; E1in.x = -E1i; E1in.y = E1i;
    f2 C2p = b2(C2), SLp = b2(SL), SRp = b2(SR), PHrp = b2(PHr);
    f2 PHin; PHin.x = -PHi; PHin.y = PHi;

    // ---- Aq for the 4 rows: U column loaded once, 4 fma pairs ----
    const float* q0 = queries + n0 * DIM;        // block-uniform
    const float* ur = U_re + (h * 2 * DIM) * DIM + j;
    const float* ui = U_im + (h * 2 * DIM) * DIM + j;
    f2 uq0 = 0.f, uq1 = 0.f, uq2 = 0.f, uq3 = 0.f;
    #pragma unroll 8
    for (int i = 0; i < DIM; ++i) {
        f2 u; u.x = ur[i * DIM]; u.y = ui[i * DIM];
        uq0 = FMA2(b2(q0[i]), u, uq0);
        uq1 = FMA2(b2(q0[DIM + i]), u, uq1);
        uq2 = FMA2(b2(q0[2 * DIM + i]), u, uq2);
        uq3 = FMA2(b2(q0[3 * DIM + i]), u, uq3);
    }

    f2 h0 = 0.f, h1 = 0.f, h2 = 0.f, h3 = 0.f;
    // single-chain packed step: identical op sequence to the verified kernel
    auto step1 = [&](f2& hS, const f2& uq, const f2& av) {
        f2 uv = uq + av;
        f2 p; p.x = dppf<SWAP1>(hS.x); p.y = dppf<SWAP1>(hS.y);
        f2 tp = FMA2(C1p, hS, S1p * p);
        f2 T  = FMA2(E1rp, tp, E1in * SW(tp));
        f2 L; L.x = dppf<WSHL1>(T.x); L.y = dppf<WSHL1>(T.y);
        f2 R; R.x = dppf<WSHR1>(T.x); R.y = dppf<WSHR1>(T.y);
        f2 sp = FMA2(C2p, T, FMA2(SLp, L, SRp * R));
        f2 z  = FMA2(PHrp, sp, FMA2(PHin, SW(sp), uv));
        float q2 = fmaf(z.x, z.x, fmaf(z.y, z.y, 1e-10f));
        float rs = __builtin_amdgcn_rsqf(q2);
        float sc = fmaxf(fmaf(bj, rs, 1.f), 0.f);
        hS = z * b2(sc);
    };
    auto step4 = [&](f2 av) {      // 4 independent chains, one shared input
        step1(h0, uq0, av);
        step1(h1, uq1, av);
        step1(h2, uq2, av);
        step1(h3, uq3, av);
    };

    // ---- scan: 64 timestep-pairs (f4 = 2 steps), batch-4 register dbuf ----
    const f4* p = AvP + (h * 512 + b * 64) * 64 + j;   // pair stride = 64 f4
    f4 buf[4], nxt[4];
    #pragma unroll
    for (int k = 0; k < 4; ++k) buf[k] = p[k * 64];

    for (int w = 0; w < 16; ++w) {
        const f4* pn = p + ((w < 15) ? 4 * 64 : 0);
        #pragma unroll
        for (int k = 0; k < 4; ++k) nxt[k] = pn[k * 64];
        p = pn;
        #pragma unroll
        for (int k = 0; k < 4; ++k) {
            f2 a; a.x = buf[k].x; a.y = buf[k].y;
            step4(a);                      // timestep 8w + 2k
            f2 d; d.x = buf[k].z; d.y = buf[k].w;
            step4(d);                      // timestep 8w + 2k + 1
        }
        #pragma unroll
        for (int k = 0; k < 4; ++k) buf[k] = nxt[k];
    }

    // ---- fused dense for rows n0..n0+3 ----
    __shared__ float s_acc[4][HEADS * DIM];   // 4 KB
    __shared__ float s_part[4][256];          // 4 KB
    s_acc[0][h * 64 + j] = h0.x;              // Re(hT)
    s_acc[1][h * 64 + j] = h1.x;
    s_acc[2][h * 64 + j] = h2.x;
    s_acc[3][h * 64 + j] = h3.x;
    __syncthreads();

    {   // thread t: k-quarter qq = t>>6, col jj = t&63; W loaded once, 4 fma
        int qq = t >> 6, jj = t & 63;
        const float* Wp = W_dense + (qq * 64) * DIM + jj;
        const float* a0 = &s_acc[0][qq * 64];
        const float* a1 = &s_acc[1][qq * 64];
        const float* a2 = &s_acc[2][qq * 64];
        const float* a3 = &s_acc[3][qq * 64];
        float p0 = 0.f, p1 = 0.f, p2 = 0.f, p3 = 0.f;
        #pragma unroll 8
        for (int k = 0; k < 64; ++k) {
            float wv = Wp[k * DIM];                 // coalesced, L2-hot
            p0 = fmaf(a0[k], wv, p0);
            p1 = fmaf(a1[k], wv, p1);
            p2 = fmaf(a2[k], wv, p2);
            p3 = fmaf(a3[k], wv, p3);
        }
        s_part[0][t] = p0;
        s_part[1][t] = p1;
        s_part[2][t] = p2;
        s_part[3][t] = p3;
    }
    __syncthreads();
    {   // 256 outputs (4 rows x 64 cols), one per thread
        int r = t >> 6, c = t & 63;
        y[(n0 + r) * DIM + c] = b_dense[c]
            + s_part[r][c] + s_part[r][64 + c]
            + s_part[r][128 + c] + s_part[r][192 + c];
    }
}

extern "C" void kernel_launch(void* const* d_in, const int* in_sizes, int n_in,
                              void* d_out, int out_size, void* d_ws, size_t ws_size,
                              hipStream_t stream) {
    const float* queries = (const float*)d_in[0];
    const float* values  = (const float*)d_in[1];
    const float* U_re    = (const float*)d_in[2];
    const float* U_im    = (const float*)d_in[3];
    const float* bias    = (const float*)d_in[4];
    const float* theta1  = (const float*)d_in[5];
    const float* phi1    = (const float*)d_in[6];
    const float* theta2  = (const float*)d_in[7];
    const float* phi2    = (const float*)d_in[8];
    const float* omega   = (const float*)d_in[9];
    const float* W_dense = (const float*)d_in[10];
    const float* b_dense = (const float*)d_in[11];
    float* y = (float*)d_out;

    f4* AvP = (f4*)d_ws;                              // 2 MB
    float* Coef = (float*)((char*)d_ws + HEADS * 512 * 64 * sizeof(f4));  // 10 KB

    k_av<<<512, 256, 0, stream>>>(values, U_re, U_im, bias, theta1, phi1,
                                  theta2, phi2, omega, AvP, Coef);
    k_rnn_dense<<<256, 256, 0, stream>>>(queries, U_re, U_im, Coef, AvP,
                                         W_dense, b_dense, y);
}

// Round 8
// 110.155 us; speedup vs baseline: 1.0919x; 1.0140x over previous
//
#include <hip/hip_runtime.h>
#include <math.h>

#define DIM 64
#define HEADS 4
#define BB 8
#define QQ 128
#define VV 128
#define NN (BB*QQ)   // 1024

typedef float f2 __attribute__((ext_vector_type(2)));
typedef float f4 __attribute__((ext_vector_type(4)));

// ---- DPP helpers (VALU, no DS); CTRL is a compile-time template constant ----
template <int CTRL>
__device__ __forceinline__ float dppf(float x) {
    return __int_as_float(__builtin_amdgcn_update_dpp(
        0, __float_as_int(x), CTRL, 0xF, 0xF, true));
}
#define SWAP1 0xB1   // quad_perm(1,0,3,2): xor-1 partner
#define WSHR1 0x138  // wave_shr:1 : lane j <- j-1
#define WSHL1 0x130  // wave_shl:1 : lane j <- j+1

__device__ __forceinline__ f2 b2(float s) { f2 r; r.x = s; r.y = s; return r; }
#define FMA2(a, b, c) __builtin_elementwise_fma((a), (b), (c))

// K1: AvP[h][rp][j] = float4 {re,im of v-row 2rp ; re,im of v-row 2rp+1}
//     (re,im)[row][j] = sum_i values[row,i] * U[h, 64+i, j]
// Block 0 additionally precomputes the per-(h,j) recurrence coefficients
// (all trig) into Coef[10][256].
__global__ __launch_bounds__(256) void k_av(const float* __restrict__ values,
                                            const float* __restrict__ U_re,
                                            const float* __restrict__ U_im,
                                            const float* __restrict__ bias,
                                            const float* __restrict__ theta1,
                                            const float* __restrict__ phi1,
                                            const float* __restrict__ theta2,
                                            const float* __restrict__ phi2,
                                            const float* __restrict__ omega,
                                            f4* __restrict__ AvP,
                                            float* __restrict__ Coef) {
    int tid = blockIdx.x * blockDim.x + threadIdx.x;
    int w = tid >> 6;            // 0..2047
    int j = tid & 63;
    int h = w >> 9;              // 0..3
    int rp = w & 511;            // v-row pair within head
    int r0 = rp << 1;
    const float* vrow = values + r0 * DIM;                     // wave-uniform
    const float* ur = U_re + (h * 2 * DIM + DIM) * DIM + j;    // bottom half
    const float* ui = U_im + (h * 2 * DIM + DIM) * DIM + j;
    f2 a0 = 0.f, a1 = 0.f;
    #pragma unroll 8
    for (int i = 0; i < DIM; ++i) {
        f2 u; u.x = ur[i * DIM]; u.y = ui[i * DIM];
        a0 += vrow[i] * u;
        a1 += vrow[DIM + i] * u;
    }
    f4 o; o.x = a0.x; o.y = a0.y; o.z = a1.x; o.w = a1.y;
    AvP[(h * 512 + rp) * 64 + j] = o;      // one dwordx4 store

    if (blockIdx.x == 0) {
        int t = threadIdx.x;
        int hh = t >> 6, jj = t & 63;
        int k1 = jj >> 1;
        float th1 = theta1[hh * 32 + k1], ph1 = phi1[hh * 32 + k1];
        float C1 = cosf(th1), s1v = sinf(th1);
        float S1, E1r, E1i;
        if ((jj & 1) == 0) { S1 = -s1v; E1r = cosf(ph1); E1i = sinf(ph1); }
        else               { S1 =  s1v; E1r = 1.f;       E1i = 0.f;       }
        float C2, SL, SR, p2r, p2i;
        if (jj == 0 || jj == 63) {
            C2 = 1.f; SL = 0.f; SR = 0.f; p2r = 1.f; p2i = 0.f;
        } else {
            int k2 = (jj - 1) >> 1;
            float th2 = theta2[hh * 31 + k2], ph2 = phi2[hh * 31 + k2];
            float c2 = cosf(th2), s2 = sinf(th2);
            if (jj & 1) { C2 = c2; SL = -s2; SR = 0.f; p2r = cosf(ph2); p2i = sinf(ph2); }
            else        { C2 = c2; SR =  s2; SL = 0.f; p2r = 1.f;       p2i = 0.f;      }
        }
        float om = omega[hh * 64 + jj];
        float eor = cosf(om), eoi = sinf(om);
        float PHr = p2r * eor - p2i * eoi;
        float PHi = p2r * eoi + p2i * eor;
        Coef[0 * 256 + t] = C1;
        Coef[1 * 256 + t] = S1;
        Coef[2 * 256 + t] = E1r;
        Coef[3 * 256 + t] = E1i;
        Coef[4 * 256 + t] = C2;
        Coef[5 * 256 + t] = SL;
        Coef[6 * 256 + t] = SR;
        Coef[7 * 256 + t] = PHr;
        Coef[8 * 256 + t] = PHi;
        Coef[9 * 256 + t] = bias[hh * 64 + jj];
    }
}

// K2: 512 blocks (query-row pair, same batch) x 4 waves (head per wave),
// 2 blocks/CU. CHAIN-MAJOR packing: hr = {row0.re, row1.re}, hi = {row0.im,
// row1.im}. Complex arithmetic needs NO cross-component shuffles (the SW()
// of the re/im packing is gone), DPP applies to whole registers, and every
// arithmetic op is a clean 2-chain v_pk_* op: ~26 pk + 12 dpp + 2 rsq per
// 2 chains per step. Arithmetic sequence per chain is identical to the
// verified kernel (fma<->fma, mul<->mul, same order) -> same results.
__global__ __launch_bounds__(256, 2) void k_rnn_dense(
        const float* __restrict__ queries,
        const float* __restrict__ U_re,
        const float* __restrict__ U_im,
        const float* __restrict__ Coef,
        const f4* __restrict__ AvP,
        const float* __restrict__ W_dense,
        const float* __restrict__ b_dense,
        float* __restrict__ y) {
    int m = blockIdx.x;        // 0..511 (row pair)
    int n0 = m << 1;           // rows n0, n0+1 (same batch b)
    int t = threadIdx.x;
    int h = t >> 6;            // head = wave
    int j = t & 63;            // state dim = lane
    int b = n0 >> 7;

    // ---- coefficients: 10 coalesced loads ----
    float C1  = Coef[0 * 256 + t];
    float S1  = Coef[1 * 256 + t];
    float E1r = Coef[2 * 256 + t];
    float E1i = Coef[3 * 256 + t];
    float C2  = Coef[4 * 256 + t];
    float SL  = Coef[5 * 256 + t];
    float SR  = Coef[6 * 256 + t];
    float PHr = Coef[7 * 256 + t];
    float PHi = Coef[8 * 256 + t];
    float bj  = Coef[9 * 256 + t];

    f2 C1p = b2(C1), S1p = b2(S1);
    f2 E1rp = b2(E1r), E1ip = b2(E1i), mE1ip = b2(-E1i);
    f2 C2p = b2(C2), SLp = b2(SL), SRp = b2(SR);
    f2 PHrp = b2(PHr), PHip = b2(PHi), mPHip = b2(-PHi);
    f2 bjp = b2(bj), onep = b2(1.f), epsp = b2(1e-10f), zerop = b2(0.f);

    // ---- Aq for both rows, chain-major: uqr = {row0.re, row1.re} etc ----
    const float* q0 = queries + n0 * DIM;        // block-uniform
    const float* q1 = q0 + DIM;
    const float* ur = U_re + (h * 2 * DIM) * DIM + j;
    const float* ui = U_im + (h * 2 * DIM) * DIM + j;
    f2 uqr = 0.f, uqi = 0.f;
    #pragma unroll 8
    for (int i = 0; i < DIM; ++i) {
        float u_r = ur[i * DIM], u_i = ui[i * DIM];
        f2 a; a.x = q0[i]; a.y = q1[i];          // {chain0, chain1}
        uqr = FMA2(a, b2(u_r), uqr);
        uqi = FMA2(a, b2(u_i), uqi);
    }

    f2 hr = 0.f, hi = 0.f;
    // one timestep for both chains; av (per-lane) shared by both chains
    auto step = [&](float avr, float avi) {
        f2 uvr = uqr + b2(avr);
        f2 uvi = uqi + b2(avi);
        // layer 1: p = swap1(h); tp = C1*h + S1*p; T = E1 (.) tp
        f2 pr, pi;
        pr.x = dppf<SWAP1>(hr.x); pr.y = dppf<SWAP1>(hr.y);
        pi.x = dppf<SWAP1>(hi.x); pi.y = dppf<SWAP1>(hi.y);
        f2 tpr = FMA2(C1p, hr, S1p * pr);
        f2 tpi = FMA2(C1p, hi, S1p * pi);
        f2 Tr = FMA2(E1rp, tpr, mE1ip * tpi);    // no shuffles: separate regs
        f2 Ti = FMA2(E1rp, tpi, E1ip * tpr);
        // layer 2: real 3-tap + fused phase
        f2 Lr, Li, Rr, Ri;
        Lr.x = dppf<WSHL1>(Tr.x); Lr.y = dppf<WSHL1>(Tr.y);
        Li.x = dppf<WSHL1>(Ti.x); Li.y = dppf<WSHL1>(Ti.y);
        Rr.x = dppf<WSHR1>(Tr.x); Rr.y = dppf<WSHR1>(Tr.y);
        Ri.x = dppf<WSHR1>(Ti.x); Ri.y = dppf<WSHR1>(Ti.y);
        f2 spr = FMA2(C2p, Tr, FMA2(SLp, Lr, SRp * Rr));
        f2 spi = FMA2(C2p, Ti, FMA2(SLp, Li, SRp * Ri));
        f2 zr = FMA2(PHrp, spr, FMA2(mPHip, spi, uvr));
        f2 zi = FMA2(PHrp, spi, FMA2(PHip, spr, uvi));
        // modrelu, 2 chains at once
        f2 q2 = FMA2(zr, zr, FMA2(zi, zi, epsp));
        f2 rs;
        rs.x = __builtin_amdgcn_rsqf(q2.x);
        rs.y = __builtin_amdgcn_rsqf(q2.y);
        f2 sc = __builtin_elementwise_max(FMA2(bjp, rs, onep), zerop);
        hr = zr * sc;
        hi = zi * sc;
    };

    // ---- scan: 64 timestep-pairs (f4 = 2 steps), batch-4 register dbuf ----
    const f4* p = AvP + (h * 512 + b * 64) * 64 + j;   // pair stride = 64 f4
    f4 buf[4], nxt[4];
    #pragma unroll
    for (int k = 0; k < 4; ++k) buf[k] = p[k * 64];

    for (int w = 0; w < 16; ++w) {
        const f4* pn = p + ((w < 15) ? 4 * 64 : 0);
        #pragma unroll
        for (int k = 0; k < 4; ++k) nxt[k] = pn[k * 64];
        p = pn;
        #pragma unroll
        for (int k = 0; k < 4; ++k) {
            step(buf[k].x, buf[k].y);      // timestep 8w + 2k
            step(buf[k].z, buf[k].w);      // timestep 8w + 2k + 1
        }
        #pragma unroll
        for (int k = 0; k < 4; ++k) buf[k] = nxt[k];
    }

    // ---- fused dense for rows n0, n0+1 ----
    __shared__ float s_acc[2][HEADS * DIM];   // 2 x 256
    __shared__ float s_part[2][256];
    s_acc[0][h * 64 + j] = hr.x;              // Re(hT) row n0 (chain 0)
    s_acc[1][h * 64 + j] = hr.y;              // Re(hT) row n0+1 (chain 1)
    __syncthreads();

    {   // thread t: k-quarter qq = t>>6, col jj = t&63; W loaded once, 2 fma
        int qq = t >> 6, jj = t & 63;
        const float* Wp = W_dense + (qq * 64) * DIM + jj;
        const float* a0 = &s_acc[0][qq * 64];
        const float* a1 = &s_acc[1][qq * 64];
        float part0 = 0.f, part1 = 0.f;
        #pragma unroll 8
        for (int k = 0; k < 64; ++k) {
            float wv = Wp[k * DIM];                 // coalesced, L2-hot
            part0 = fmaf(a0[k], wv, part0);         // LDS broadcast
            part1 = fmaf(a1[k], wv, part1);
        }
        s_part[0][t] = part0;
        s_part[1][t] = part1;
    }
    __syncthreads();
    if (t < 128) {
        int r = t >> 6, c = t & 63;
        y[(n0 + r) * DIM + c] = b_dense[c]
            + s_part[r][c] + s_part[r][64 + c]
            + s_part[r][128 + c] + s_part[r][192 + c];
    }
}

extern "C" void kernel_launch(void* const* d_in, const int* in_sizes, int n_in,
                              void* d_out, int out_size, void* d_ws, size_t ws_size,
                              hipStream_t stream) {
    const float* queries = (const float*)d_in[0];
    const float* values  = (const float*)d_in[1];
    const float* U_re    = (const float*)d_in[2];
    const float* U_im    = (const float*)d_in[3];
    const float* bias    = (const float*)d_in[4];
    const float* theta1  = (const float*)d_in[5];
    const float* phi1    = (const float*)d_in[6];
    const float* theta2  = (const float*)d_in[7];
    const float* phi2    = (const float*)d_in[8];
    const float* omega   = (const float*)d_in[9];
    const float* W_dense = (const float*)d_in[10];
    const float* b_dense = (const float*)d_in[11];
    float* y = (float*)d_out;

    f4* AvP = (f4*)d_ws;                              // 2 MB
    float* Coef = (float*)((char*)d_ws + HEADS * 512 * 64 * sizeof(f4));  // 10 KB

    k_av<<<512, 256, 0, stream>>>(values, U_re, U_im, bias, theta1, phi1,
                                  theta2, phi2, omega, AvP, Coef);
    k_rnn_dense<<<512, 256, 0, stream>>>(queries, U_re, U_im, Coef, AvP,
                                         W_dense, b_dense, y);
}